// Round 7
// baseline (1563.031 us; speedup 1.0000x reference)
//
#include <hip/hip_runtime.h>
#include <hip/hip_bf16.h>
#include <cstdint>
#include <cstddef>

#define BB   16
#define NN   4096
#define DD   128
#define SS   1024
#define CIN  131
#define C1   256
#define MM   (SS*16)

#define FP 168   // Fs pitch (bf16 elems)
#define AP 264   // As pitch

typedef __attribute__((ext_vector_type(8))) short bf16x8;
typedef __attribute__((ext_vector_type(4))) float f32x4;

__device__ __forceinline__ float bf2f(unsigned short u) {
  union { unsigned int i; float f; } x; x.i = ((unsigned int)u) << 16; return x.f;
}
__device__ __forceinline__ unsigned short f2bf(float f) {
  union { __hip_bfloat16 h; unsigned short u; } c; c.h = __float2bfloat16(f); return c.u;
}

// ---------------- weight convert ----------------
__global__ __launch_bounds__(256) void convert_kernel(
    const float* __restrict__ W1, const float* __restrict__ W2,
    unsigned short* __restrict__ W1b, unsigned short* __restrict__ W2b)
{
  const int n = blockIdx.x, t = threadIdx.x;
  if (t < 160) {
    float v = 0.0f;
    if (t < 128)      v = W1[n*CIN + 3 + t];
    else if (t < 131) v = W1[n*CIN + (t - 128)];
    W1b[n*160 + t] = f2bf(v);
  }
  W2b[n*256 + t] = f2bf(W2[n*256 + t]);
}

// ---------------- FPS v4: 256 thr, obuf (no per-iter global store), coord-carry,
// f32 DPP max fast path + exact u64 fallback on ties ----------------
__global__ __launch_bounds__(256) void fps_kernel(
    const float* __restrict__ xyz, float* __restrict__ out_xyz)
{
  __shared__ float xs[NN], ys[NN], zs[NN];
  __shared__ float obuf[SS*3];
  __shared__ unsigned int wbuf[2][4][8];
  const int b = blockIdx.x;
  const int tid = threadIdx.x;
  const int wave = tid >> 6, lane = tid & 63;
  const float* base = xyz + (size_t)b * NN * 3;
  for (int i = tid; i < NN; i += 256) {
    xs[i] = base[i*3+0]; ys[i] = base[i*3+1]; zs[i] = base[i*3+2];
  }
  __syncthreads();
  float px[16], py[16], pz[16], mind[16];
  #pragma unroll
  for (int j = 0; j < 16; ++j) {
    px[j] = xs[j*256 + tid];
    py[j] = ys[j*256 + tid];
    pz[j] = zs[j*256 + tid];
    mind[j] = 1e10f;
  }
  float cx = xs[0], cy = ys[0], cz = zs[0];
  for (int it = 0; it < SS; ++it) {
    if (tid == 0) { obuf[it*3+0] = cx; obuf[it*3+1] = cy; obuf[it*3+2] = cz; }
    float bv = -1.0f; int bj = 0;
    #pragma unroll
    for (int j = 0; j < 16; ++j) {
      float dx = __fsub_rn(px[j], cx);
      float dy = __fsub_rn(py[j], cy);
      float dz = __fsub_rn(pz[j], cz);
      float d  = __fadd_rn(__fadd_rn(__fmul_rn(dx,dx), __fmul_rn(dy,dy)), __fmul_rn(dz,dz));
      float md = fminf(mind[j], d);
      mind[j] = md;
      if (md > bv) { bv = md; bj = j; }   // strict >: earliest j wins -> smallest idx
    }
    const int myidx = bj*256 + tid;
    // fast path: wave max of bv via 1-inst DPP max steps
    float wm = bv;
    #define FMAX_STEP(CTRL) { \
      int t_ = __builtin_amdgcn_update_dpp(__float_as_int(wm), __float_as_int(wm), CTRL, 0xf, 0xf, false); \
      wm = fmaxf(wm, __int_as_float(t_)); }
    FMAX_STEP(0x111) FMAX_STEP(0x112) FMAX_STEP(0x114) FMAX_STEP(0x118)
    FMAX_STEP(0x142) FMAX_STEP(0x143)
    #undef FMAX_STEP
    const float wmax = __int_as_float(__builtin_amdgcn_readlane(__float_as_int(wm), 63));
    const unsigned long long mask = __ballot(bv == wmax);
    const int par = it & 1;
    bool iwr;
    if (__popcll(mask) == 1) {
      iwr = ((mask >> lane) & 1ull) != 0ull;
    } else {
      // tie among lanes: exact u64 (dist, ~idx) reduce for smallest-idx semantics
      unsigned long long best = ((unsigned long long)__float_as_uint(bv) << 32)
                              | (unsigned int)(~(unsigned int)myidx);
      const unsigned long long mykey = best;
      #define KMAX_STEP(CTRL) { \
        unsigned int lo = (unsigned int)best, hi = (unsigned int)(best >> 32); \
        unsigned int lo2 = (unsigned int)__builtin_amdgcn_update_dpp((int)lo, (int)lo, CTRL, 0xf, 0xf, false); \
        unsigned int hi2 = (unsigned int)__builtin_amdgcn_update_dpp((int)hi, (int)hi, CTRL, 0xf, 0xf, false); \
        unsigned long long o = (((unsigned long long)hi2) << 32) | lo2; \
        if (o > best) best = o; }
      KMAX_STEP(0x111) KMAX_STEP(0x112) KMAX_STEP(0x114) KMAX_STEP(0x118)
      KMAX_STEP(0x142) KMAX_STEP(0x143)
      #undef KMAX_STEP
      unsigned int klo = (unsigned int)__builtin_amdgcn_readlane((int)(unsigned int)best, 63);
      unsigned int khi = (unsigned int)__builtin_amdgcn_readlane((int)(best >> 32), 63);
      iwr = (mykey == ((((unsigned long long)khi) << 32) | klo));
    }
    if (iwr) {
      unsigned int* slot = &wbuf[par][wave][0];
      slot[0] = ~(unsigned int)myidx;       // key lo
      slot[1] = __float_as_uint(bv);        // key hi (dist)
      slot[2] = __float_as_uint(xs[myidx]);
      slot[3] = __float_as_uint(ys[myidx]);
      slot[4] = __float_as_uint(zs[myidx]);
    }
    __syncthreads();
    unsigned long long gk = 0ull; float gx = cx, gy = cy, gz = cz;
    #pragma unroll
    for (int w = 0; w < 4; ++w) {
      const uint4 a = *(const uint4*)&wbuf[par][w][0];
      const unsigned int zz = wbuf[par][w][4];
      const unsigned long long k = (((unsigned long long)a.y) << 32) | a.x;
      if (k > gk) { gk = k; gx = __uint_as_float(a.z); gy = __uint_as_float(a.w); gz = __uint_as_float(zz); }
    }
    cx = gx; cy = gy; cz = gz;
  }
  __syncthreads();
  for (int i = tid; i < SS*3; i += 256) out_xyz[b*SS*3 + i] = obuf[i];
}

// ---------------- kNN: batched ds_read_b128, 8 points/step ----------------
__global__ __launch_bounds__(64) void knn_kernel(
    const float* __restrict__ xyz, const float* __restrict__ new_xyz, int* __restrict__ knn_idx)
{
  __shared__ __align__(16) float tile[1536];
  const int b = blockIdx.y;
  const int s = (blockIdx.x << 6) + threadIdx.x;
  const float cx = new_xyz[((b<<10)+s)*3+0];
  const float cy = new_xyz[((b<<10)+s)*3+1];
  const float cz = new_xyz[((b<<10)+s)*3+2];
  float td[16]; int ti[16];
  #pragma unroll
  for (int j = 0; j < 16; ++j) { td[j] = 3.4e38f; ti[j] = 0; }
  const float4* gbase = (const float4*)(xyz + (size_t)b*NN*3);
  for (int t0 = 0; t0 < NN; t0 += 512) {
    __syncthreads();
    {
      const float4* src = gbase + ((t0*3) >> 2);
      float4* dst = (float4*)tile;
      #pragma unroll
      for (int k = 0; k < 6; ++k) dst[threadIdx.x + k*64] = src[threadIdx.x + k*64];
    }
    __syncthreads();
    for (int i0 = 0; i0 < 512; i0 += 8) {
      const float4 v0 = *(const float4*)&tile[i0*3 +  0];
      const float4 v1 = *(const float4*)&tile[i0*3 +  4];
      const float4 v2 = *(const float4*)&tile[i0*3 +  8];
      const float4 v3 = *(const float4*)&tile[i0*3 + 12];
      const float4 v4 = *(const float4*)&tile[i0*3 + 16];
      const float4 v5 = *(const float4*)&tile[i0*3 + 20];
      float d[8];
      #define KDIST(slot, X, Y, Z) { \
        float dx = __fsub_rn(X, cx); \
        float dy = __fsub_rn(Y, cy); \
        float dz = __fsub_rn(Z, cz); \
        d[slot] = __fadd_rn(__fadd_rn(__fmul_rn(dx,dx), __fmul_rn(dy,dy)), __fmul_rn(dz,dz)); }
      KDIST(0, v0.x, v0.y, v0.z)
      KDIST(1, v0.w, v1.x, v1.y)
      KDIST(2, v1.z, v1.w, v2.x)
      KDIST(3, v2.y, v2.z, v2.w)
      KDIST(4, v3.x, v3.y, v3.z)
      KDIST(5, v3.w, v4.x, v4.y)
      KDIST(6, v4.z, v4.w, v5.x)
      KDIST(7, v5.y, v5.z, v5.w)
      #undef KDIST
      #pragma unroll
      for (int j = 0; j < 8; ++j) {
        if (d[j] < td[15]) {
          td[15] = d[j]; ti[15] = t0 + i0 + j;
          #pragma unroll
          for (int q = 15; q > 0; --q) {
            if (td[q] < td[q-1]) {
              float tf = td[q]; td[q] = td[q-1]; td[q-1] = tf;
              int   tt = ti[q]; ti[q] = ti[q-1]; ti[q-1] = tt;
            }
          }
        }
      }
    }
  }
  int* o = knn_idx + ((size_t)((b<<10)+s))*16;
  #pragma unroll
  for (int j = 0; j < 16; ++j) o[j] = ti[j];
}

// ---- helper: stage gathered feature tile into LDS ----
__device__ __forceinline__ void stage_features(
    unsigned short* Fs, const float* xyz, const float* points,
    const int* knn_idx, const float* new_xyz, int b, int by, int tid)
{
  const int rg = tid >> 2, cg = tid & 3;
  const int m = by*64 + rg;
  const int s = m >> 4, kk = m & 15;
  const int p = knn_idx[((b<<10)+s)*16 + kk];
  const float4* pb = (const float4*)(points + ((size_t)b*NN + p) * DD);
  unsigned short* row = Fs + rg*FP;
  #pragma unroll
  for (int i = 0; i < 8; ++i) {
    float4 v = pb[cg*8 + i];
    ushort4 u;
    u.x = f2bf(v.x); u.y = f2bf(v.y); u.z = f2bf(v.z); u.w = f2bf(v.w);
    *(ushort4*)&row[cg*32 + i*4] = u;
  }
  if (cg == 0) {
    float c3[3];
    c3[0] = xyz[((size_t)b*NN + p)*3+0] - new_xyz[((b<<10)+s)*3+0];
    c3[1] = xyz[((size_t)b*NN + p)*3+1] - new_xyz[((b<<10)+s)*3+1];
    c3[2] = xyz[((size_t)b*NN + p)*3+2] - new_xyz[((b<<10)+s)*3+2];
    #pragma unroll
    for (int k = 128; k < 160; k += 4) {
      ushort4 u;
      u.x = f2bf(k+0 < 131 ? c3[k-128+0] : 0.0f);
      u.y = f2bf(k+1 < 131 ? c3[k-128+1] : 0.0f);
      u.z = f2bf(k+2 < 131 ? c3[k-128+2] : 0.0f);
      u.w = f2bf(k+3 < 131 ? c3[k-128+3] : 0.0f);
      *(ushort4*)&row[k] = u;
    }
  }
}

// ---------------- pass A: y1 (MFMA, B from global) -> BN1 partials ----------------
__global__ __launch_bounds__(256, 2) void gemm1_stats_kernel(
    const float* __restrict__ xyz, const float* __restrict__ points,
    const unsigned short* __restrict__ W1b, const float* __restrict__ bias1,
    const int* __restrict__ knn_idx, const float* __restrict__ new_xyz,
    float* __restrict__ Psum, float* __restrict__ Psq)
{
  __shared__ unsigned short Fs[64*FP];
  __shared__ float RedS[1024];
  __shared__ float RedQ[1024];
  const int by = blockIdx.x, b = blockIdx.y;
  const int tid = threadIdx.x;
  const int wave = tid >> 6, lane = tid & 63;
  const int m15 = lane & 15, quad = lane >> 4;
  const int n0w = wave * 64;

  stage_features(Fs, xyz, points, knn_idx, new_xyz, b, by, tid);
  __syncthreads();

  f32x4 acc[4][4];
  #pragma unroll
  for (int t = 0; t < 4; ++t)
    #pragma unroll
    for (int u = 0; u < 4; ++u) acc[t][u] = (f32x4){0.f,0.f,0.f,0.f};

  #pragma unroll
  for (int kc = 0; kc < 5; ++kc) {
    const int k0 = kc * 32;
    bf16x8 af[4], bfr[4];
    #pragma unroll
    for (int u = 0; u < 4; ++u)
      bfr[u] = *(const bf16x8*)&W1b[(size_t)(n0w + u*16 + m15)*160 + k0 + quad*8];
    #pragma unroll
    for (int t = 0; t < 4; ++t)
      af[t] = *(const bf16x8*)&Fs[(t*16 + m15)*FP + k0 + quad*8];
    #pragma unroll
    for (int t = 0; t < 4; ++t)
      #pragma unroll
      for (int u = 0; u < 4; ++u)
        acc[t][u] = __builtin_amdgcn_mfma_f32_16x16x32_bf16(af[t], bfr[u], acc[t][u], 0, 0, 0);
  }

  #pragma unroll
  for (int u = 0; u < 4; ++u) {
    const int n = n0w + u*16 + m15;
    const float bias = bias1[n];
    float ps = 0.f, pq = 0.f;
    #pragma unroll
    for (int t = 0; t < 4; ++t)
      #pragma unroll
      for (int r = 0; r < 4; ++r) {
        float y = acc[t][u][r] + bias;
        ps += y; pq += y*y;
      }
    RedS[n*4 + quad] = ps;
    RedQ[n*4 + quad] = pq;
  }
  __syncthreads();
  {
    const int n = tid;
    float4 s4 = *(const float4*)&RedS[n*4];
    float4 q4 = *(const float4*)&RedQ[n*4];
    const int row = b*256 + by;
    Psum[(size_t)n*4096 + row] = (s4.x + s4.y) + (s4.z + s4.w);
    Psq [(size_t)n*4096 + row] = (q4.x + q4.y) + (q4.z + q4.w);
  }
}

// ---------------- stats ----------------
__global__ __launch_bounds__(256) void stats_kernel(
    const float* __restrict__ Psum, const float* __restrict__ Psq,
    const float* __restrict__ gamma, const float* __restrict__ beta,
    float* __restrict__ scale, float* __restrict__ shift)
{
  __shared__ float sv[4], qv[4];
  const int c = blockIdx.x, tid = threadIdx.x;
  float s = 0.f, q = 0.f;
  for (int r = tid; r < 4096; r += 256) { s += Psum[(size_t)c*4096+r]; q += Psq[(size_t)c*4096+r]; }
  #pragma unroll
  for (int off = 32; off > 0; off >>= 1) { s += __shfl_down(s, off); q += __shfl_down(q, off); }
  if ((tid & 63) == 0) { sv[tid>>6] = s; qv[tid>>6] = q; }
  __syncthreads();
  if (tid == 0) {
    s = sv[0]+sv[1]+sv[2]+sv[3]; q = qv[0]+qv[1]+qv[2]+qv[3];
    const float count = 262144.0f;
    float mean = s / count;
    float var  = fmaxf(q / count - mean*mean, 0.0f);
    float inv  = 1.0f / sqrtf(var + 1e-5f);
    float sc   = gamma[c] * inv;
    scale[c] = sc;
    shift[c] = beta[c] - mean * sc;
  }
}

// ---------------- fused: y1 (MFMA) -> bn1+relu -> y2 (MFMA) -> BN2 partials + max/min ----------------
__global__ __launch_bounds__(256, 2) void fused2_kernel(
    const float* __restrict__ xyz, const float* __restrict__ points,
    const unsigned short* __restrict__ W1b, const float* __restrict__ bias1,
    const int* __restrict__ knn_idx, const float* __restrict__ new_xyz,
    const float* __restrict__ sc1v, const float* __restrict__ sh1v,
    const unsigned short* __restrict__ W2b, const float* __restrict__ bias2,
    float* __restrict__ maxv, float* __restrict__ minv,
    float* __restrict__ Psum, float* __restrict__ Psq)
{
  __shared__ char smem[58368];
  unsigned short* As_  = (unsigned short*)smem;            // 64*264*2 = 33792 (aliases Fs)
  unsigned short* Fs   = (unsigned short*)smem;            // 64*168*2 = 21504
  float* RedS  = (float*)(smem + 33792);                   // 4096
  float* RedQ  = (float*)(smem + 37888);                   // 4096
  float* MMBuf = (float*)(smem + 41984);                   // 16384

  const int by = blockIdx.x, b = blockIdx.y;
  const int tid = threadIdx.x;
  const int wave = tid >> 6, lane = tid & 63;
  const int m15 = lane & 15, quad = lane >> 4;
  const int n0w = wave * 64;

  stage_features(Fs, xyz, points, knn_idx, new_xyz, b, by, tid);
  __syncthreads();

  f32x4 acc[4][4];
  #pragma unroll
  for (int t = 0; t < 4; ++t)
    #pragma unroll
    for (int u = 0; u < 4; ++u) acc[t][u] = (f32x4){0.f,0.f,0.f,0.f};

  // ---- stage 1: y1 = F @ W1^T (B from global) ----
  #pragma unroll
  for (int kc = 0; kc < 5; ++kc) {
    const int k0 = kc * 32;
    bf16x8 af[4], bfr[4];
    #pragma unroll
    for (int u = 0; u < 4; ++u)
      bfr[u] = *(const bf16x8*)&W1b[(size_t)(n0w + u*16 + m15)*160 + k0 + quad*8];
    #pragma unroll
    for (int t = 0; t < 4; ++t)
      af[t] = *(const bf16x8*)&Fs[(t*16 + m15)*FP + k0 + quad*8];
    #pragma unroll
    for (int t = 0; t < 4; ++t)
      #pragma unroll
      for (int u = 0; u < 4; ++u)
        acc[t][u] = __builtin_amdgcn_mfma_f32_16x16x32_bf16(af[t], bfr[u], acc[t][u], 0, 0, 0);
  }

  __syncthreads();   // all Fs reads done before As overwrites it

  #pragma unroll
  for (int u = 0; u < 4; ++u) {
    const int n = n0w + u*16 + m15;
    const float bias = bias1[n], sc = sc1v[n], sh = sh1v[n];
    #pragma unroll
    for (int t = 0; t < 4; ++t)
      #pragma unroll
      for (int r = 0; r < 4; ++r) {
        float a = fmaxf((acc[t][u][r] + bias)*sc + sh, 0.0f);
        As_[(t*16 + quad*4 + r)*AP + n] = f2bf(a);
      }
  }

  #pragma unroll
  for (int t = 0; t < 4; ++t)
    #pragma unroll
    for (int u = 0; u < 4; ++u) acc[t][u] = (f32x4){0.f,0.f,0.f,0.f};

  __syncthreads();   // As complete before stage 2 reads

  // ---- stage 2: y2 = A @ W2^T (B from global) ----
  #pragma unroll
  for (int kc = 0; kc < 8; ++kc) {
    const int k0 = kc * 32;
    bf16x8 af[4], bfr[4];
    #pragma unroll
    for (int u = 0; u < 4; ++u)
      bfr[u] = *(const bf16x8*)&W2b[(size_t)(n0w + u*16 + m15)*256 + k0 + quad*8];
    #pragma unroll
    for (int t = 0; t < 4; ++t)
      af[t] = *(const bf16x8*)&As_[(t*16 + m15)*AP + k0 + quad*8];
    #pragma unroll
    for (int t = 0; t < 4; ++t)
      #pragma unroll
      for (int u = 0; u < 4; ++u)
        acc[t][u] = __builtin_amdgcn_mfma_f32_16x16x32_bf16(af[t], bfr[u], acc[t][u], 0, 0, 0);
  }

  float mxv[4][4], mnv[4][4];
  #pragma unroll
  for (int u = 0; u < 4; ++u) {
    const int n = n0w + u*16 + m15;
    const float bias = bias2[n];
    float ps = 0.f, pq = 0.f;
    #pragma unroll
    for (int t = 0; t < 4; ++t) {
      float y0 = acc[t][u][0] + bias, y1 = acc[t][u][1] + bias;
      float y2 = acc[t][u][2] + bias, y3 = acc[t][u][3] + bias;
      ps += ((y0 + y1) + (y2 + y3));
      pq += ((y0*y0 + y1*y1) + (y2*y2 + y3*y3));
      mxv[t][u] = fmaxf(fmaxf(y0, y1), fmaxf(y2, y3));
      mnv[t][u] = fminf(fminf(y0, y1), fminf(y2, y3));
    }
    RedS[n*4 + quad] = ps;
    RedQ[n*4 + quad] = pq;
    #pragma unroll
    for (int t = 0; t < 4; ++t) MMBuf[(t*256 + n)*4 + quad] = mxv[t][u];
  }
  __syncthreads();
  {
    const int n = tid;
    float4 s4 = *(const float4*)&RedS[n*4];
    float4 q4 = *(const float4*)&RedQ[n*4];
    const int row = b*256 + by;
    Psum[(size_t)n*4096 + row] = (s4.x + s4.y) + (s4.z + s4.w);
    Psq [(size_t)n*4096 + row] = (q4.x + q4.y) + (q4.z + q4.w);
    #pragma unroll
    for (int j = 0; j < 4; ++j) {
      float4 m4 = *(const float4*)&MMBuf[(j*256 + n)*4];
      float v = fmaxf(fmaxf(m4.x, m4.y), fmaxf(m4.z, m4.w));
      maxv[((size_t)((b<<10) + by*4 + j))*C1 + n] = v;
    }
  }
  __syncthreads();
  #pragma unroll
  for (int u = 0; u < 4; ++u) {
    const int n = n0w + u*16 + m15;
    #pragma unroll
    for (int t = 0; t < 4; ++t) MMBuf[(t*256 + n)*4 + quad] = mnv[t][u];
  }
  __syncthreads();
  {
    const int n = tid;
    #pragma unroll
    for (int j = 0; j < 4; ++j) {
      float4 m4 = *(const float4*)&MMBuf[(j*256 + n)*4];
      float v = fminf(fminf(m4.x, m4.y), fminf(m4.z, m4.w));
      minv[((size_t)((b<<10) + by*4 + j))*C1 + n] = v;
    }
  }
}

// ---------------- final ----------------
__global__ __launch_bounds__(256) void final_kernel(
    const float* __restrict__ maxv, const float* __restrict__ minv,
    const float* __restrict__ scale2, const float* __restrict__ shift2,
    float* __restrict__ out)
{
  const int bs = blockIdx.x;
  const int n  = threadIdx.x;
  const float sc = scale2[n], sh = shift2[n];
  const size_t idx = (size_t)bs * C1 + n;
  const float sel = (sc >= 0.0f) ? maxv[idx] : minv[idx];
  out[(size_t)BB*SS*3 + idx] = fmaxf(sc*sel + sh, 0.0f);
}

extern "C" void kernel_launch(void* const* d_in, const int* in_sizes, int n_in,
                              void* d_out, int out_size, void* d_ws, size_t ws_size,
                              hipStream_t stream) {
  const float* xyz    = (const float*)d_in[0];
  const float* points = (const float*)d_in[1];
  const float* W1     = (const float*)d_in[2];
  const float* b1     = (const float*)d_in[3];
  const float* g1     = (const float*)d_in[4];
  const float* bt1    = (const float*)d_in[5];
  const float* W2     = (const float*)d_in[6];
  const float* b2     = (const float*)d_in[7];
  const float* g2     = (const float*)d_in[8];
  const float* bt2    = (const float*)d_in[9];
  float* out = (float*)d_out;
  char* ws = (char*)d_ws;

  int*   knn_idx = (int*)(ws + 0);
  float* Ps      = (float*)(ws + 1048576ULL);
  float* Pq      = (float*)(ws + 5242880ULL);
  float* sc1     = (float*)(ws + 9437184ULL);
  float* sh1     = (float*)(ws + 9438208ULL);
  float* sc2     = (float*)(ws + 9439232ULL);
  float* sh2     = (float*)(ws + 9440256ULL);
  float* maxv    = (float*)(ws + 9441280ULL);
  float* minv    = (float*)(ws + 26218496ULL);
  unsigned short* W1b = (unsigned short*)(ws + 42995712ULL);
  unsigned short* W2b = (unsigned short*)(ws + 43077632ULL);

  float* new_xyz = out;

  convert_kernel<<<256, 256, 0, stream>>>(W1, W2, W1b, W2b);
  fps_kernel<<<BB, 256, 0, stream>>>(xyz, new_xyz);
  knn_kernel<<<dim3(16, BB), 64, 0, stream>>>(xyz, new_xyz, knn_idx);
  gemm1_stats_kernel<<<dim3(256, BB), 256, 0, stream>>>(xyz, points, W1b, b1, knn_idx, new_xyz, Ps, Pq);
  stats_kernel<<<256, 256, 0, stream>>>(Ps, Pq, g1, bt1, sc1, sh1);
  fused2_kernel<<<dim3(256, BB), 256, 0, stream>>>(xyz, points, W1b, b1, knn_idx, new_xyz,
                                                   sc1, sh1, W2b, b2, maxv, minv, Ps, Pq);
  stats_kernel<<<256, 256, 0, stream>>>(Ps, Pq, g2, bt2, sc2, sh2);
  final_kernel<<<BB*SS, 256, 0, stream>>>(maxv, minv, sc2, sh2, out);
}

// Round 8
// 1090.794 us; speedup vs baseline: 1.4329x; 1.4329x over previous
//
#include <hip/hip_runtime.h>
#include <hip/hip_bf16.h>
#include <cstdint>
#include <cstddef>

#define BB   16
#define NN   4096
#define DD   128
#define SS   1024
#define CIN  131
#define C1   256
#define MM   (SS*16)

#define FP 168   // Fs pitch (bf16 elems)
#define AP 264   // As pitch

typedef __attribute__((ext_vector_type(8))) short bf16x8;
typedef __attribute__((ext_vector_type(4))) float f32x4;

__device__ __forceinline__ float bf2f(unsigned short u) {
  union { unsigned int i; float f; } x; x.i = ((unsigned int)u) << 16; return x.f;
}
__device__ __forceinline__ unsigned short f2bf(float f) {
  union { __hip_bfloat16 h; unsigned short u; } c; c.h = __float2bfloat16(f); return c.u;
}

// ---------------- weight convert ----------------
__global__ __launch_bounds__(256) void convert_kernel(
    const float* __restrict__ W1, const float* __restrict__ W2,
    unsigned short* __restrict__ W1b, unsigned short* __restrict__ W2b)
{
  const int n = blockIdx.x, t = threadIdx.x;
  if (t < 160) {
    float v = 0.0f;
    if (t < 128)      v = W1[n*CIN + 3 + t];
    else if (t < 131) v = W1[n*CIN + (t - 128)];
    W1b[n*160 + t] = f2bf(v);
  }
  W2b[n*256 + t] = f2bf(W2[n*256 + t]);
}

// ---------------- FPS (R5-measured-best): 256 threads, 16 pts/thread in registers, u64 DPP ----------------
__global__ __launch_bounds__(256) void fps_kernel(
    const float* __restrict__ xyz, float* __restrict__ out_xyz)
{
  __shared__ float xs[NN], ys[NN], zs[NN];
  __shared__ unsigned long long wres[2][4];
  const int b = blockIdx.x;
  const int tid = threadIdx.x;
  const int wave = tid >> 6, lane = tid & 63;
  const float* base = xyz + (size_t)b * NN * 3;
  for (int i = tid; i < NN; i += 256) {
    xs[i] = base[i*3+0]; ys[i] = base[i*3+1]; zs[i] = base[i*3+2];
  }
  __syncthreads();
  float px[16], py[16], pz[16], mind[16];
  #pragma unroll
  for (int j = 0; j < 16; ++j) {
    px[j] = xs[j*256 + tid];
    py[j] = ys[j*256 + tid];
    pz[j] = zs[j*256 + tid];
    mind[j] = 1e10f;
  }
  int far = 0;
  for (int it = 0; it < SS; ++it) {
    if (tid == 0) {
      out_xyz[(b*SS + it)*3 + 0] = xs[far];
      out_xyz[(b*SS + it)*3 + 1] = ys[far];
      out_xyz[(b*SS + it)*3 + 2] = zs[far];
    }
    const float cx = xs[far], cy = ys[far], cz = zs[far];
    float bv = -1.0f; int bj = 0;
    #pragma unroll
    for (int j = 0; j < 16; ++j) {
      float dx = __fsub_rn(px[j], cx);
      float dy = __fsub_rn(py[j], cy);
      float dz = __fsub_rn(pz[j], cz);
      float d  = __fadd_rn(__fadd_rn(__fmul_rn(dx,dx), __fmul_rn(dy,dy)), __fmul_rn(dz,dz));
      float md = fminf(mind[j], d);
      mind[j] = md;
      if (md > bv) { bv = md; bj = j; }   // strict >: earliest j wins -> smallest idx
    }
    unsigned long long best = ((unsigned long long)__float_as_uint(bv) << 32)
                            | (unsigned int)(~(unsigned int)(bj*256 + tid));
    #define FPS_STEP(CTRL) { \
      unsigned int lo = (unsigned int)best, hi = (unsigned int)(best >> 32); \
      unsigned int lo2 = (unsigned int)__builtin_amdgcn_update_dpp((int)lo, (int)lo, CTRL, 0xf, 0xf, false); \
      unsigned int hi2 = (unsigned int)__builtin_amdgcn_update_dpp((int)hi, (int)hi, CTRL, 0xf, 0xf, false); \
      unsigned long long o = (((unsigned long long)hi2) << 32) | lo2; \
      if (o > best) best = o; }
    FPS_STEP(0x111) FPS_STEP(0x112) FPS_STEP(0x114) FPS_STEP(0x118)
    FPS_STEP(0x142) FPS_STEP(0x143)
    #undef FPS_STEP
    const int par = it & 1;
    if (lane == 63) wres[par][wave] = best;
    __syncthreads();
    unsigned long long g = wres[par][0];
    #pragma unroll
    for (int w = 1; w < 4; ++w) {
      unsigned long long o = wres[par][w];
      if (o > g) g = o;
    }
    far = (int)(~(unsigned int)g);
  }
}

// ---------------- kNN v3: 256 thr/block, 4 threads per query, full point set in LDS ----------------
__global__ __launch_bounds__(256) void knn_kernel(
    const float* __restrict__ xyz, const float* __restrict__ new_xyz, int* __restrict__ knn_idx)
{
  __shared__ __align__(16) float tile[12288];   // 48 KB: all 4096 pts x 3 floats
  const int b = blockIdx.y;
  const int tid = threadIdx.x;
  const int q = tid >> 2, c = tid & 3;          // query-in-block, quarter
  const int s = blockIdx.x * 64 + q;
  // stage all 4096 points, coalesced float4
  {
    const float4* src = (const float4*)(xyz + (size_t)b*NN*3);
    float4* dst = (float4*)tile;
    #pragma unroll
    for (int k = 0; k < 12; ++k) dst[tid + k*256] = src[tid + k*256];
  }
  const float cx = new_xyz[((b<<10)+s)*3+0];
  const float cy = new_xyz[((b<<10)+s)*3+1];
  const float cz = new_xyz[((b<<10)+s)*3+2];
  float td[16]; int ti[16];
  #pragma unroll
  for (int j = 0; j < 16; ++j) { td[j] = 3.4e38f; ti[j] = 0; }
  __syncthreads();
  const float* base = tile + c*3072;            // quarter c: points [c*1024, c*1024+1024)
  for (int i0 = 0; i0 < 1024; i0 += 8) {
    const float4 v0 = *(const float4*)&base[i0*3 +  0];
    const float4 v1 = *(const float4*)&base[i0*3 +  4];
    const float4 v2 = *(const float4*)&base[i0*3 +  8];
    const float4 v3 = *(const float4*)&base[i0*3 + 12];
    const float4 v4 = *(const float4*)&base[i0*3 + 16];
    const float4 v5 = *(const float4*)&base[i0*3 + 20];
    float d[8];
    #define KDIST(slot, X, Y, Z) { \
      float dx = __fsub_rn(X, cx); \
      float dy = __fsub_rn(Y, cy); \
      float dz = __fsub_rn(Z, cz); \
      d[slot] = __fadd_rn(__fadd_rn(__fmul_rn(dx,dx), __fmul_rn(dy,dy)), __fmul_rn(dz,dz)); }
    KDIST(0, v0.x, v0.y, v0.z)
    KDIST(1, v0.w, v1.x, v1.y)
    KDIST(2, v1.z, v1.w, v2.x)
    KDIST(3, v2.y, v2.z, v2.w)
    KDIST(4, v3.x, v3.y, v3.z)
    KDIST(5, v3.w, v4.x, v4.y)
    KDIST(6, v4.z, v4.w, v5.x)
    KDIST(7, v5.y, v5.z, v5.w)
    #undef KDIST
    #pragma unroll
    for (int j = 0; j < 8; ++j) {
      if (d[j] < td[15]) {
        td[15] = d[j]; ti[15] = c*1024 + i0 + j;
        #pragma unroll
        for (int p = 15; p > 0; --p) {
          if (td[p] < td[p-1]) {
            float tf = td[p]; td[p] = td[p-1]; td[p-1] = tf;
            int   tt = ti[p]; ti[p] = ti[p-1]; ti[p-1] = tt;
          }
        }
      }
    }
  }
  __syncthreads();                              // scans done: reuse tile as merge buffers
  float* dbuf = tile;                           // 256*17 floats
  int*   ibuf = (int*)(tile + 4352);            // 256*17 ints
  #pragma unroll
  for (int j = 0; j < 16; ++j) { dbuf[tid*17 + j] = td[j]; ibuf[tid*17 + j] = ti[j]; }
  __syncthreads();
  if (c == 0) {
    int h0 = 0, h1 = 0, h2 = 0, h3 = 0;
    const int s0 = (q*4+0)*17, s1 = (q*4+1)*17, s2 = (q*4+2)*17, s3 = (q*4+3)*17;
    int* o = knn_idx + ((size_t)((b<<10)+s))*16;
    #pragma unroll
    for (int out = 0; out < 16; ++out) {
      float d0 = dbuf[s0+h0], d1 = dbuf[s1+h1], d2 = dbuf[s2+h2], d3 = dbuf[s3+h3];
      float bd = d0; int bc = 0;
      if (d1 < bd) { bd = d1; bc = 1; }       // strict <: earlier quarter wins ties
      if (d2 < bd) { bd = d2; bc = 2; }
      if (d3 < bd) { bd = d3; bc = 3; }
      int idx;
      if      (bc == 0) { idx = ibuf[s0+h0]; ++h0; }
      else if (bc == 1) { idx = ibuf[s1+h1]; ++h1; }
      else if (bc == 2) { idx = ibuf[s2+h2]; ++h2; }
      else              { idx = ibuf[s3+h3]; ++h3; }
      o[out] = idx;
    }
  }
}

// ---- helper: stage gathered feature tile into LDS ----
__device__ __forceinline__ void stage_features(
    unsigned short* Fs, const float* xyz, const float* points,
    const int* knn_idx, const float* new_xyz, int b, int by, int tid)
{
  const int rg = tid >> 2, cg = tid & 3;
  const int m = by*64 + rg;
  const int s = m >> 4, kk = m & 15;
  const int p = knn_idx[((b<<10)+s)*16 + kk];
  const float4* pb = (const float4*)(points + ((size_t)b*NN + p) * DD);
  unsigned short* row = Fs + rg*FP;
  #pragma unroll
  for (int i = 0; i < 8; ++i) {
    float4 v = pb[cg*8 + i];
    ushort4 u;
    u.x = f2bf(v.x); u.y = f2bf(v.y); u.z = f2bf(v.z); u.w = f2bf(v.w);
    *(ushort4*)&row[cg*32 + i*4] = u;
  }
  if (cg == 0) {
    float c3[3];
    c3[0] = xyz[((size_t)b*NN + p)*3+0] - new_xyz[((b<<10)+s)*3+0];
    c3[1] = xyz[((size_t)b*NN + p)*3+1] - new_xyz[((b<<10)+s)*3+1];
    c3[2] = xyz[((size_t)b*NN + p)*3+2] - new_xyz[((b<<10)+s)*3+2];
    #pragma unroll
    for (int k = 128; k < 160; k += 4) {
      ushort4 u;
      u.x = f2bf(k+0 < 131 ? c3[k-128+0] : 0.0f);
      u.y = f2bf(k+1 < 131 ? c3[k-128+1] : 0.0f);
      u.z = f2bf(k+2 < 131 ? c3[k-128+2] : 0.0f);
      u.w = f2bf(k+3 < 131 ? c3[k-128+3] : 0.0f);
      *(ushort4*)&row[k] = u;
    }
  }
}

// ---------------- pass A: y1 (MFMA, B from global) -> BN1 partials ----------------
__global__ __launch_bounds__(256, 2) void gemm1_stats_kernel(
    const float* __restrict__ xyz, const float* __restrict__ points,
    const unsigned short* __restrict__ W1b, const float* __restrict__ bias1,
    const int* __restrict__ knn_idx, const float* __restrict__ new_xyz,
    float* __restrict__ Psum, float* __restrict__ Psq)
{
  __shared__ unsigned short Fs[64*FP];
  __shared__ float RedS[1024];
  __shared__ float RedQ[1024];
  const int by = blockIdx.x, b = blockIdx.y;
  const int tid = threadIdx.x;
  const int wave = tid >> 6, lane = tid & 63;
  const int m15 = lane & 15, quad = lane >> 4;
  const int n0w = wave * 64;

  stage_features(Fs, xyz, points, knn_idx, new_xyz, b, by, tid);
  __syncthreads();

  f32x4 acc[4][4];
  #pragma unroll
  for (int t = 0; t < 4; ++t)
    #pragma unroll
    for (int u = 0; u < 4; ++u) acc[t][u] = (f32x4){0.f,0.f,0.f,0.f};

  #pragma unroll
  for (int kc = 0; kc < 5; ++kc) {
    const int k0 = kc * 32;
    bf16x8 af[4], bfr[4];
    #pragma unroll
    for (int u = 0; u < 4; ++u)
      bfr[u] = *(const bf16x8*)&W1b[(size_t)(n0w + u*16 + m15)*160 + k0 + quad*8];
    #pragma unroll
    for (int t = 0; t < 4; ++t)
      af[t] = *(const bf16x8*)&Fs[(t*16 + m15)*FP + k0 + quad*8];
    #pragma unroll
    for (int t = 0; t < 4; ++t)
      #pragma unroll
      for (int u = 0; u < 4; ++u)
        acc[t][u] = __builtin_amdgcn_mfma_f32_16x16x32_bf16(af[t], bfr[u], acc[t][u], 0, 0, 0);
  }

  #pragma unroll
  for (int u = 0; u < 4; ++u) {
    const int n = n0w + u*16 + m15;
    const float bias = bias1[n];
    float ps = 0.f, pq = 0.f;
    #pragma unroll
    for (int t = 0; t < 4; ++t)
      #pragma unroll
      for (int r = 0; r < 4; ++r) {
        float y = acc[t][u][r] + bias;
        ps += y; pq += y*y;
      }
    RedS[n*4 + quad] = ps;
    RedQ[n*4 + quad] = pq;
  }
  __syncthreads();
  {
    const int n = tid;
    float4 s4 = *(const float4*)&RedS[n*4];
    float4 q4 = *(const float4*)&RedQ[n*4];
    const int row = b*256 + by;
    Psum[(size_t)n*4096 + row] = (s4.x + s4.y) + (s4.z + s4.w);
    Psq [(size_t)n*4096 + row] = (q4.x + q4.y) + (q4.z + q4.w);
  }
}

// ---------------- stats ----------------
__global__ __launch_bounds__(256) void stats_kernel(
    const float* __restrict__ Psum, const float* __restrict__ Psq,
    const float* __restrict__ gamma, const float* __restrict__ beta,
    float* __restrict__ scale, float* __restrict__ shift)
{
  __shared__ float sv[4], qv[4];
  const int c = blockIdx.x, tid = threadIdx.x;
  float s = 0.f, q = 0.f;
  for (int r = tid; r < 4096; r += 256) { s += Psum[(size_t)c*4096+r]; q += Psq[(size_t)c*4096+r]; }
  #pragma unroll
  for (int off = 32; off > 0; off >>= 1) { s += __shfl_down(s, off); q += __shfl_down(q, off); }
  if ((tid & 63) == 0) { sv[tid>>6] = s; qv[tid>>6] = q; }
  __syncthreads();
  if (tid == 0) {
    s = sv[0]+sv[1]+sv[2]+sv[3]; q = qv[0]+qv[1]+qv[2]+qv[3];
    const float count = 262144.0f;
    float mean = s / count;
    float var  = fmaxf(q / count - mean*mean, 0.0f);
    float inv  = 1.0f / sqrtf(var + 1e-5f);
    float sc   = gamma[c] * inv;
    scale[c] = sc;
    shift[c] = beta[c] - mean * sc;
  }
}

// ---------------- fused: y1 (MFMA) -> bn1+relu -> y2 (MFMA) -> BN2 partials + max/min ----------------
__global__ __launch_bounds__(256, 2) void fused2_kernel(
    const float* __restrict__ xyz, const float* __restrict__ points,
    const unsigned short* __restrict__ W1b, const float* __restrict__ bias1,
    const int* __restrict__ knn_idx, const float* __restrict__ new_xyz,
    const float* __restrict__ sc1v, const float* __restrict__ sh1v,
    const unsigned short* __restrict__ W2b, const float* __restrict__ bias2,
    float* __restrict__ maxv, float* __restrict__ minv,
    float* __restrict__ Psum, float* __restrict__ Psq)
{
  __shared__ char smem[58368];
  unsigned short* As_  = (unsigned short*)smem;            // 64*264*2 = 33792 (aliases Fs)
  unsigned short* Fs   = (unsigned short*)smem;            // 64*168*2 = 21504
  float* RedS  = (float*)(smem + 33792);                   // 4096
  float* RedQ  = (float*)(smem + 37888);                   // 4096
  float* MMBuf = (float*)(smem + 41984);                   // 16384

  const int by = blockIdx.x, b = blockIdx.y;
  const int tid = threadIdx.x;
  const int wave = tid >> 6, lane = tid & 63;
  const int m15 = lane & 15, quad = lane >> 4;
  const int n0w = wave * 64;

  stage_features(Fs, xyz, points, knn_idx, new_xyz, b, by, tid);
  __syncthreads();

  f32x4 acc[4][4];
  #pragma unroll
  for (int t = 0; t < 4; ++t)
    #pragma unroll
    for (int u = 0; u < 4; ++u) acc[t][u] = (f32x4){0.f,0.f,0.f,0.f};

  // ---- stage 1: y1 = F @ W1^T (B from global) ----
  #pragma unroll
  for (int kc = 0; kc < 5; ++kc) {
    const int k0 = kc * 32;
    bf16x8 af[4], bfr[4];
    #pragma unroll
    for (int u = 0; u < 4; ++u)
      bfr[u] = *(const bf16x8*)&W1b[(size_t)(n0w + u*16 + m15)*160 + k0 + quad*8];
    #pragma unroll
    for (int t = 0; t < 4; ++t)
      af[t] = *(const bf16x8*)&Fs[(t*16 + m15)*FP + k0 + quad*8];
    #pragma unroll
    for (int t = 0; t < 4; ++t)
      #pragma unroll
      for (int u = 0; u < 4; ++u)
        acc[t][u] = __builtin_amdgcn_mfma_f32_16x16x32_bf16(af[t], bfr[u], acc[t][u], 0, 0, 0);
  }

  __syncthreads();   // all Fs reads done before As overwrites it

  #pragma unroll
  for (int u = 0; u < 4; ++u) {
    const int n = n0w + u*16 + m15;
    const float bias = bias1[n], sc = sc1v[n], sh = sh1v[n];
    #pragma unroll
    for (int t = 0; t < 4; ++t)
      #pragma unroll
      for (int r = 0; r < 4; ++r) {
        float a = fmaxf((acc[t][u][r] + bias)*sc + sh, 0.0f);
        As_[(t*16 + quad*4 + r)*AP + n] = f2bf(a);
      }
  }

  #pragma unroll
  for (int t = 0; t < 4; ++t)
    #pragma unroll
    for (int u = 0; u < 4; ++u) acc[t][u] = (f32x4){0.f,0.f,0.f,0.f};

  __syncthreads();   // As complete before stage 2 reads

  // ---- stage 2: y2 = A @ W2^T (B from global) ----
  #pragma unroll
  for (int kc = 0; kc < 8; ++kc) {
    const int k0 = kc * 32;
    bf16x8 af[4], bfr[4];
    #pragma unroll
    for (int u = 0; u < 4; ++u)
      bfr[u] = *(const bf16x8*)&W2b[(size_t)(n0w + u*16 + m15)*256 + k0 + quad*8];
    #pragma unroll
    for (int t = 0; t < 4; ++t)
      af[t] = *(const bf16x8*)&As_[(t*16 + m15)*AP + k0 + quad*8];
    #pragma unroll
    for (int t = 0; t < 4; ++t)
      #pragma unroll
      for (int u = 0; u < 4; ++u)
        acc[t][u] = __builtin_amdgcn_mfma_f32_16x16x32_bf16(af[t], bfr[u], acc[t][u], 0, 0, 0);
  }

  float mxv[4][4], mnv[4][4];
  #pragma unroll
  for (int u = 0; u < 4; ++u) {
    const int n = n0w + u*16 + m15;
    const float bias = bias2[n];
    float ps = 0.f, pq = 0.f;
    #pragma unroll
    for (int t = 0; t < 4; ++t) {
      float y0 = acc[t][u][0] + bias, y1 = acc[t][u][1] + bias;
      float y2 = acc[t][u][2] + bias, y3 = acc[t][u][3] + bias;
      ps += ((y0 + y1) + (y2 + y3));
      pq += ((y0*y0 + y1*y1) + (y2*y2 + y3*y3));
      mxv[t][u] = fmaxf(fmaxf(y0, y1), fmaxf(y2, y3));
      mnv[t][u] = fminf(fminf(y0, y1), fminf(y2, y3));
    }
    RedS[n*4 + quad] = ps;
    RedQ[n*4 + quad] = pq;
    #pragma unroll
    for (int t = 0; t < 4; ++t) MMBuf[(t*256 + n)*4 + quad] = mxv[t][u];
  }
  __syncthreads();
  {
    const int n = tid;
    float4 s4 = *(const float4*)&RedS[n*4];
    float4 q4 = *(const float4*)&RedQ[n*4];
    const int row = b*256 + by;
    Psum[(size_t)n*4096 + row] = (s4.x + s4.y) + (s4.z + s4.w);
    Psq [(size_t)n*4096 + row] = (q4.x + q4.y) + (q4.z + q4.w);
    #pragma unroll
    for (int j = 0; j < 4; ++j) {
      float4 m4 = *(const float4*)&MMBuf[(j*256 + n)*4];
      float v = fmaxf(fmaxf(m4.x, m4.y), fmaxf(m4.z, m4.w));
      maxv[((size_t)((b<<10) + by*4 + j))*C1 + n] = v;
    }
  }
  __syncthreads();
  #pragma unroll
  for (int u = 0; u < 4; ++u) {
    const int n = n0w + u*16 + m15;
    #pragma unroll
    for (int t = 0; t < 4; ++t) MMBuf[(t*256 + n)*4 + quad] = mnv[t][u];
  }
  __syncthreads();
  {
    const int n = tid;
    #pragma unroll
    for (int j = 0; j < 4; ++j) {
      float4 m4 = *(const float4*)&MMBuf[(j*256 + n)*4];
      float v = fminf(fminf(m4.x, m4.y), fminf(m4.z, m4.w));
      minv[((size_t)((b<<10) + by*4 + j))*C1 + n] = v;
    }
  }
}

// ---------------- final ----------------
__global__ __launch_bounds__(256) void final_kernel(
    const float* __restrict__ maxv, const float* __restrict__ minv,
    const float* __restrict__ scale2, const float* __restrict__ shift2,
    float* __restrict__ out)
{
  const int bs = blockIdx.x;
  const int n  = threadIdx.x;
  const float sc = scale2[n], sh = shift2[n];
  const size_t idx = (size_t)bs * C1 + n;
  const float sel = (sc >= 0.0f) ? maxv[idx] : minv[idx];
  out[(size_t)BB*SS*3 + idx] = fmaxf(sc*sel + sh, 0.0f);
}

extern "C" void kernel_launch(void* const* d_in, const int* in_sizes, int n_in,
                              void* d_out, int out_size, void* d_ws, size_t ws_size,
                              hipStream_t stream) {
  const float* xyz    = (const float*)d_in[0];
  const float* points = (const float*)d_in[1];
  const float* W1     = (const float*)d_in[2];
  const float* b1     = (const float*)d_in[3];
  const float* g1     = (const float*)d_in[4];
  const float* bt1    = (const float*)d_in[5];
  const float* W2     = (const float*)d_in[6];
  const float* b2     = (const float*)d_in[7];
  const float* g2     = (const float*)d_in[8];
  const float* bt2    = (const float*)d_in[9];
  float* out = (float*)d_out;
  char* ws = (char*)d_ws;

  int*   knn_idx = (int*)(ws + 0);
  float* Ps      = (float*)(ws + 1048576ULL);
  float* Pq      = (float*)(ws + 5242880ULL);
  float* sc1     = (float*)(ws + 9437184ULL);
  float* sh1     = (float*)(ws + 9438208ULL);
  float* sc2     = (float*)(ws + 9439232ULL);
  float* sh2     = (float*)(ws + 9440256ULL);
  float* maxv    = (float*)(ws + 9441280ULL);
  float* minv    = (float*)(ws + 26218496ULL);
  unsigned short* W1b = (unsigned short*)(ws + 42995712ULL);
  unsigned short* W2b = (unsigned short*)(ws + 43077632ULL);

  float* new_xyz = out;

  convert_kernel<<<256, 256, 0, stream>>>(W1, W2, W1b, W2b);
  fps_kernel<<<BB, 256, 0, stream>>>(xyz, new_xyz);
  knn_kernel<<<dim3(16, BB), 256, 0, stream>>>(xyz, new_xyz, knn_idx);
  gemm1_stats_kernel<<<dim3(256, BB), 256, 0, stream>>>(xyz, points, W1b, b1, knn_idx, new_xyz, Ps, Pq);
  stats_kernel<<<256, 256, 0, stream>>>(Ps, Pq, g1, bt1, sc1, sh1);
  fused2_kernel<<<dim3(256, BB), 256, 0, stream>>>(xyz, points, W1b, b1, knn_idx, new_xyz,
                                                   sc1, sh1, W2b, b2, maxv, minv, Ps, Pq);
  stats_kernel<<<256, 256, 0, stream>>>(Ps, Pq, g2, bt2, sc2, sh2);
  final_kernel<<<BB*SS, 256, 0, stream>>>(maxv, minv, sc2, sh2, out);
}